// Round 5
// baseline (267.147 us; speedup 1.0000x reference)
//
#include <hip/hip_runtime.h>
#include <stdint.h>

#define NQ 4096
#define NCAM 6
#define NV 22050
#define M_TOTAL (NCAM * NV) /* 132300 */

typedef __bf16 bf16x8 __attribute__((ext_vector_type(8)));
typedef float f32x4 __attribute__((ext_vector_type(4)));
typedef unsigned int u32x4 __attribute__((ext_vector_type(4)));

__device__ __forceinline__ unsigned short f2bf(float f) {
    union { float f; uint32_t u; } v; v.f = f;
    uint32_t u = v.u;
    uint32_t r = (u + 0x7FFFu + ((u >> 16) & 1u)) >> 16;
    return (unsigned short)r;
}
__device__ __forceinline__ float bf_lo(uint32_t u) {
    union { uint32_t u; float f; } v; v.u = u << 16; return v.f;
}
__device__ __forceinline__ float bf_hi(uint32_t u) {
    union { uint32_t u; float f; } v; v.u = u & 0xFFFF0000u; return v.f;
}
__device__ __forceinline__ int imin(int a, int b) { return a < b ? a : b; }
__device__ __forceinline__ int imax(int a, int b) { return a > b ? a : b; }

// ---------------- Wv transpose + bf16 convert (tiny) ----------------
__global__ void wvt_kernel(const float* __restrict__ Wv, unsigned short* __restrict__ WvT) {
    int n = blockIdx.x, k = threadIdx.x;
    WvT[n * 256 + k] = f2bf(Wv[k * 256 + n]);
}

// ---------------- value projection GEMM: val = value @ Wv + bv (bf16 MFMA) ----------------
// LDS-free: both MFMA fragments load straight from global (A: value rows, 32B f32
// per lane, quads read contiguous 128B lines; B: WvT rows, 16B per lane, L2-resident).
// Operand order SWAPPED (mfma(Wv_frag, value_frag)) so each lane's C/D holds 4
// consecutive channels of one pixel -> epilogue store = one aligned dwordx2 into
// the per-(cam,head) plane layout val2[c][h][pix][32ch].
__global__ __launch_bounds__(256) void val_gemm(const float* __restrict__ A,
                                                const unsigned short* __restrict__ BT,
                                                const float* __restrict__ bv,
                                                unsigned short* __restrict__ C) {
    const int t = threadIdx.x;
    const int w = t >> 6, lane = t & 63;
    const int r = lane & 15, g = lane >> 4;
    const int m_base = blockIdx.x * 64;

    f32x4 acc[4][4];   // [mi][ni]
#pragma unroll
    for (int i = 0; i < 4; ++i)
#pragma unroll
        for (int j = 0; j < 4; ++j) acc[i][j] = (f32x4)0.0f;

    const float* arow[4];
#pragma unroll
    for (int mi = 0; mi < 4; ++mi)
        arow[mi] = A + (size_t)imin(m_base + mi * 16 + r, M_TOTAL - 1) * 256 + g * 8;
    const unsigned short* brow[4];
#pragma unroll
    for (int ni = 0; ni < 4; ++ni)
        brow[ni] = BT + (size_t)(w * 64 + ni * 16 + r) * 256 + g * 8;

#pragma unroll 2
    for (int ks = 0; ks < 8; ++ks) {
        bf16x8 bfrag[4];
#pragma unroll
        for (int ni = 0; ni < 4; ++ni)
            bfrag[ni] = __builtin_bit_cast(bf16x8,
                *reinterpret_cast<const u32x4*>(brow[ni] + ks * 32));
        bf16x8 afrag[4];
#pragma unroll
        for (int mi = 0; mi < 4; ++mi) {
            float4 lo = *reinterpret_cast<const float4*>(arow[mi] + ks * 32);
            float4 hi = *reinterpret_cast<const float4*>(arow[mi] + ks * 32 + 4);
            bf16x8 av;
            av[0] = (__bf16)lo.x; av[1] = (__bf16)lo.y;
            av[2] = (__bf16)lo.z; av[3] = (__bf16)lo.w;
            av[4] = (__bf16)hi.x; av[5] = (__bf16)hi.y;
            av[6] = (__bf16)hi.z; av[7] = (__bf16)hi.w;
            afrag[mi] = av;
        }
#pragma unroll
        for (int mi = 0; mi < 4; ++mi)
#pragma unroll
            for (int ni = 0; ni < 4; ++ni)
                acc[mi][ni] = __builtin_amdgcn_mfma_f32_16x16x32_bf16(
                    bfrag[ni], afrag[mi], acc[mi][ni], 0, 0, 0);
    }

    // Epilogue: lane holds C[m = m_base+mi*16+r][n0..n0+3], n0 = w*64+ni*16+g*4.
#pragma unroll
    for (int ni = 0; ni < 4; ++ni) {
        const int n0 = w * 64 + ni * 16 + g * 4;
        const float4 bb = *reinterpret_cast<const float4*>(bv + n0);
        const int hp = n0 >> 5, cc = n0 & 31;
#pragma unroll
        for (int mi = 0; mi < 4; ++mi) {
            int m = m_base + mi * 16 + r;
            if (m < M_TOTAL) {
                unsigned int um = (unsigned int)m;
                unsigned int c = um / 22050u;
                unsigned int pix = um - c * 22050u;
                uint2 pk;
                pk.x = (uint32_t)f2bf(acc[mi][ni][0] + bb.x) |
                       ((uint32_t)f2bf(acc[mi][ni][1] + bb.y) << 16);
                pk.y = (uint32_t)f2bf(acc[mi][ni][2] + bb.z) |
                       ((uint32_t)f2bf(acc[mi][ni][3] + bb.w) << 16);
                *reinterpret_cast<uint2*>(
                    C + (((size_t)c * 8 + hp) * NV + pix) * 32 + cc) = pk;
            }
        }
    }
}

// ---------------- offsets + attention weights (q-only, cam-independent) ----------------
__global__ __launch_bounds__(256) void proj_kernel(const float* __restrict__ query,
                                                   const float* __restrict__ qpos,
                                                   const float* __restrict__ Ws,
                                                   const float* __restrict__ b_off,
                                                   const float* __restrict__ Wa,
                                                   const float* __restrict__ ba,
                                                   float* __restrict__ off_ws,
                                                   float* __restrict__ aw_ws) {
    __shared__ float qrow[4][256];
    __shared__ float logits[4][192];
    const int t = threadIdx.x;
    const int qb = blockIdx.x * 4;
#pragma unroll
    for (int j = 0; j < 4; ++j)
        qrow[j][t] = query[(size_t)(qb + j) * 256 + t] + qpos[(size_t)(qb + j) * 256 + t];
    __syncthreads();

    const float invn[3][2] = {{1.f / 168.f, 1.f / 100.f},
                              {1.f / 84.f, 1.f / 50.f},
                              {1.f / 42.f, 1.f / 25.f}};
#pragma unroll
    for (int pass = 0; pass < 3; ++pass) {
        int u = t + pass * 256;
        if (u < 384) {
            float a0 = 0.f, a1 = 0.f, a2 = 0.f, a3 = 0.f;
            for (int k = 0; k < 256; ++k) {
                float w = Ws[k * 384 + u];
                a0 += qrow[0][k] * w; a1 += qrow[1][k] * w;
                a2 += qrow[2][k] * w; a3 += qrow[3][k] * w;
            }
            int lp = u >> 1;               // (h*3+l)*8+p
            int l = (lp >> 3) % 3;
            float inv = invn[l][u & 1];
            float b = b_off[u];
            off_ws[(size_t)(qb + 0) * 384 + u] = (a0 + b) * inv;
            off_ws[(size_t)(qb + 1) * 384 + u] = (a1 + b) * inv;
            off_ws[(size_t)(qb + 2) * 384 + u] = (a2 + b) * inv;
            off_ws[(size_t)(qb + 3) * 384 + u] = (a3 + b) * inv;
        } else if (u < 576) {
            int u2 = u - 384;
            float a0 = 0.f, a1 = 0.f, a2 = 0.f, a3 = 0.f;
            for (int k = 0; k < 256; ++k) {
                float w = Wa[k * 192 + u2];
                a0 += qrow[0][k] * w; a1 += qrow[1][k] * w;
                a2 += qrow[2][k] * w; a3 += qrow[3][k] * w;
            }
            float b = ba[u2];
            logits[0][u2] = a0 + b; logits[1][u2] = a1 + b;
            logits[2][u2] = a2 + b; logits[3][u2] = a3 + b;
        }
    }
    __syncthreads();
    if (t < 32) {
        int jq = t >> 3, h = t & 7;
        float mx = -1e30f;
#pragma unroll
        for (int i = 0; i < 24; ++i) mx = fmaxf(mx, logits[jq][h * 24 + i]);
        float e[24];
        float s = 0.f;
#pragma unroll
        for (int i = 0; i < 24; ++i) { e[i] = __expf(logits[jq][h * 24 + i] - mx); s += e[i]; }
        float inv = 1.0f / s;
#pragma unroll
        for (int i = 0; i < 24; ++i)
            aw_ws[((size_t)(qb + jq) * 8 + h) * 24 + i] = e[i] * inv;
    }
}

// ---------------- bilinear sampling: one (cam,head) plane per block ----------------
__global__ __launch_bounds__(256) void sample_kernel(const unsigned short* __restrict__ val,
                                                     const float* __restrict__ rpc,
                                                     const float* __restrict__ off_ws,
                                                     const float* __restrict__ aw_ws,
                                                     unsigned short* __restrict__ out_cam) {
    const int t = threadIdx.x;
    const int qs = t >> 2;          // 64 q-slots per block
    const int sub = t & 3;          // channel quad within head
    const int p = blockIdx.x;       // 3072 blocks = 8 XCD x 6 groups x 64
    const int x = p & 7;
    const int g = x + 8 * (p >> 9);     // group = c*8 + h
    const int wblk = (p >> 3) & 63;
    const int c = g >> 3, h = g & 7;
    const int q = wblk * 64 + qs;
    const int pair = c * NQ + q;

    float refx[4], refy[4];
    const float* rp = rpc + (size_t)pair * 8;
#pragma unroll
    for (int a = 0; a < 4; ++a) { refx[a] = rp[2 * a]; refy[a] = rp[2 * a + 1]; }

    const unsigned short* vbase = val + (size_t)g * NV * 32 + sub * 8;
    const float* offp = off_ws + (size_t)q * 384 + h * 48;   // [l][p][2]
    const float* awp = aw_ws + ((size_t)q * 8 + h) * 24;

    float acc[8];
#pragma unroll
    for (int i = 0; i < 8; ++i) acc[i] = 0.f;

    const int lw[3] = {168, 84, 42};
    const int lhh[3] = {100, 50, 25};
    const int lst[3] = {0, 16800, 21000};

#pragma unroll
    for (int l = 0; l < 3; ++l) {
        const int w = lw[l], hh = lhh[l];
        const float wf = (float)w, hf = (float)hh;
        const unsigned short* vlev = vbase + (size_t)lst[l] * 32;
#pragma unroll
        for (int pt = 0; pt < 8; ++pt) {
            const int a = pt & 3;
            float ox = offp[(l * 8 + pt) * 2 + 0];
            float oy = offp[(l * 8 + pt) * 2 + 1];
            float xx = fmaf(refx[a] + ox, wf, -0.5f);
            float yy = fmaf(refy[a] + oy, hf, -0.5f);
            float xf = floorf(xx), yf = floorf(yy);
            float lx = xx - xf, ly = yy - yf;
            int x0 = (int)xf, y0 = (int)yf;
            float aww = awp[l * 8 + pt];

            float wx0 = (x0 >= 0 && x0 < w) ? (1.f - lx) : 0.f;
            float wx1 = (x0 >= -1 && x0 < w - 1) ? lx : 0.f;
            float wy0 = ((y0 >= 0 && y0 < hh) ? (1.f - ly) : 0.f) * aww;
            float wy1 = ((y0 >= -1 && y0 < hh - 1) ? ly : 0.f) * aww;

            int x0c = imin(imax(x0, 0), w - 1);
            int x1c = imin(imax(x0 + 1, 0), w - 1);
            int y0c = imin(imax(y0, 0), hh - 1);
            int y1c = imin(imax(y0 + 1, 0), hh - 1);

            int r0 = y0c * w, r1 = y1c * w;
            u32x4 u00 = *reinterpret_cast<const u32x4*>(vlev + (size_t)(r0 + x0c) * 32);
            u32x4 u10 = *reinterpret_cast<const u32x4*>(vlev + (size_t)(r0 + x1c) * 32);
            u32x4 u01 = *reinterpret_cast<const u32x4*>(vlev + (size_t)(r1 + x0c) * 32);
            u32x4 u11 = *reinterpret_cast<const u32x4*>(vlev + (size_t)(r1 + x1c) * 32);

            float w00 = wx0 * wy0, w10 = wx1 * wy0, w01 = wx0 * wy1, w11 = wx1 * wy1;
#pragma unroll
            for (int i = 0; i < 4; ++i) {
                acc[2 * i] += w00 * bf_lo(u00[i]) + w10 * bf_lo(u10[i]) +
                              w01 * bf_lo(u01[i]) + w11 * bf_lo(u11[i]);
                acc[2 * i + 1] += w00 * bf_hi(u00[i]) + w10 * bf_hi(u10[i]) +
                                  w01 * bf_hi(u01[i]) + w11 * bf_hi(u11[i]);
            }
        }
    }

    u32x4 o;
#pragma unroll
    for (int i = 0; i < 4; ++i)
        o[i] = (uint32_t)f2bf(acc[2 * i]) | ((uint32_t)f2bf(acc[2 * i + 1]) << 16);
    *reinterpret_cast<u32x4*>(out_cam + (size_t)pair * 256 + h * 32 + sub * 8) = o;
}

// ---------------- mask-combine over cams + output projection + residual ----------------
__global__ __launch_bounds__(256) void combine_kernel(const unsigned short* __restrict__ out_cam,
                                                      const unsigned char* __restrict__ bev_mask,
                                                      const float* __restrict__ Wo,
                                                      const float* __restrict__ bo,
                                                      const float* __restrict__ query,
                                                      float* __restrict__ out) {
    __shared__ float s_lds[8][256];
    __shared__ unsigned int hitm[8];
    __shared__ float invc[8];
    const int t = threadIdx.x;
    const int qb = blockIdx.x * 8;

    if (t < 8) {
        int q = qb + t;
        unsigned int m = 0;
        int cnt = 0;
        for (int c = 0; c < 6; ++c) {
            const unsigned char* bm = bev_mask + ((size_t)c * NQ + q) * 4;
            if (bm[0] | bm[1] | bm[2] | bm[3]) { m |= (1u << c); cnt++; }
        }
        hitm[t] = m;
        invc[t] = 1.0f / (float)imax(cnt, 1);
    }
    __syncthreads();
#pragma unroll
    for (int j = 0; j < 8; ++j) {
        unsigned int m = hitm[j];
        float ic = invc[j];
        float s = 0.f;
#pragma unroll
        for (int c = 0; c < 6; ++c)
            if ((m >> c) & 1u) {
                unsigned short u = out_cam[((size_t)c * NQ + qb + j) * 256 + t];
                union { uint32_t u; float f; } v; v.u = ((uint32_t)u) << 16;
                s += v.f;
            }
        s_lds[j][t] = s * ic;
    }
    __syncthreads();
    float acc[8] = {0.f, 0.f, 0.f, 0.f, 0.f, 0.f, 0.f, 0.f};
    for (int k = 0; k < 256; ++k) {
        float wv = Wo[k * 256 + t];
#pragma unroll
        for (int j = 0; j < 8; ++j) acc[j] += s_lds[j][k] * wv;
    }
    float bb = bo[t];
#pragma unroll
    for (int j = 0; j < 8; ++j)
        out[(size_t)(qb + j) * 256 + t] = acc[j] + bb + query[(size_t)(qb + j) * 256 + t];
}

extern "C" void kernel_launch(void* const* d_in, const int* in_sizes, int n_in,
                              void* d_out, int out_size, void* d_ws, size_t ws_size,
                              hipStream_t stream) {
    const float* query = (const float*)d_in[0];
    const float* value = (const float*)d_in[2];
    const float* qpos = (const float*)d_in[3];
    const float* rpc = (const float*)d_in[4];
    const unsigned char* bev = (const unsigned char*)d_in[5];
    const float* Wv = (const float*)d_in[8];
    const float* bv = (const float*)d_in[9];
    const float* Ws = (const float*)d_in[10];
    const float* b_off = (const float*)d_in[11];
    const float* Wa = (const float*)d_in[12];
    const float* ba = (const float*)d_in[13];
    const float* Wo = (const float*)d_in[14];
    const float* bo = (const float*)d_in[15];
    float* out = (float*)d_out;

    char* ws = (char*)d_ws;
    unsigned short* val_ws = (unsigned short*)ws;                        // 67,737,600 B
    size_t o = 67737600;
    float* off_ws = (float*)(ws + o);            o += 6291456;           // 4096*384*4
    float* aw_ws = (float*)(ws + o);             o += 3145728;           // 4096*192*4
    unsigned short* out_cam = (unsigned short*)(ws + o); o += 12582912;  // 6*4096*256*2
    unsigned short* WvT = (unsigned short*)(ws + o);                     // 131,072 B

    wvt_kernel<<<256, 256, 0, stream>>>(Wv, WvT);
    proj_kernel<<<NQ / 4, 256, 0, stream>>>(query, qpos, Ws, b_off, Wa, ba, off_ws, aw_ws);
    val_gemm<<<(M_TOTAL + 63) / 64, 256, 0, stream>>>(value, WvT, bv, val_ws);
    sample_kernel<<<3072, 256, 0, stream>>>(val_ws, rpc, off_ws, aw_ws, out_cam);
    combine_kernel<<<NQ / 8, 256, 0, stream>>>(out_cam, bev, Wo, bo, query, out);
}

// Round 6
// 258.122 us; speedup vs baseline: 1.0350x; 1.0350x over previous
//
#include <hip/hip_runtime.h>
#include <stdint.h>

#define NQ 4096
#define NCAM 6
#define NV 22050
#define M_TOTAL (NCAM * NV) /* 132300 */

typedef __bf16 bf16x8 __attribute__((ext_vector_type(8)));
typedef float f32x4 __attribute__((ext_vector_type(4)));
typedef unsigned int u32x4 __attribute__((ext_vector_type(4)));

__device__ __forceinline__ unsigned short f2bf(float f) {
    union { float f; uint32_t u; } v; v.f = f;
    uint32_t u = v.u;
    uint32_t r = (u + 0x7FFFu + ((u >> 16) & 1u)) >> 16;
    return (unsigned short)r;
}
__device__ __forceinline__ float bf_lo(uint32_t u) {
    union { uint32_t u; float f; } v; v.u = u << 16; return v.f;
}
__device__ __forceinline__ float bf_hi(uint32_t u) {
    union { uint32_t u; float f; } v; v.u = u & 0xFFFF0000u; return v.f;
}
__device__ __forceinline__ int imin(int a, int b) { return a < b ? a : b; }
__device__ __forceinline__ int imax(int a, int b) { return a > b ? a : b; }

// ---------------- Wv transpose + bf16 convert (tiny) ----------------
__global__ void wvt_kernel(const float* __restrict__ Wv, unsigned short* __restrict__ WvT) {
    int n = blockIdx.x, k = threadIdx.x;
    WvT[n * 256 + k] = f2bf(Wv[k * 256 + n]);
}

// ---------------- value projection GEMM: val = value @ Wv + bv (bf16 MFMA) ----------------
// Main loop LDS-free (compulsory-FETCH proven in r5). Epilogue: acc -> padded LDS
// tile -> 8 contiguous 4KB chunk stores into the per-(cam,head) plane layout
// val2[c][h][pix][32ch] (block's 64 pixels are consecutive within each plane).
__global__ __launch_bounds__(256) void val_gemm(const float* __restrict__ A,
                                                const unsigned short* __restrict__ BT,
                                                const float* __restrict__ bv,
                                                unsigned short* __restrict__ C) {
    __shared__ unsigned char clds[64 * 528];   // 64 rows x 256ch x 2B, row pad to 528B
    const int t = threadIdx.x;
    const int w = t >> 6, lane = t & 63;
    const int r = lane & 15, g = lane >> 4;
    const int m_base = blockIdx.x * 64;

    f32x4 acc[4][4];   // [mi][ni]
#pragma unroll
    for (int i = 0; i < 4; ++i)
#pragma unroll
        for (int j = 0; j < 4; ++j) acc[i][j] = (f32x4)0.0f;

    const float* arow[4];
#pragma unroll
    for (int mi = 0; mi < 4; ++mi)
        arow[mi] = A + (size_t)imin(m_base + mi * 16 + r, M_TOTAL - 1) * 256 + g * 8;
    const unsigned short* brow[4];
#pragma unroll
    for (int ni = 0; ni < 4; ++ni)
        brow[ni] = BT + (size_t)(w * 64 + ni * 16 + r) * 256 + g * 8;

#pragma unroll 2
    for (int ks = 0; ks < 8; ++ks) {
        bf16x8 bfrag[4];
#pragma unroll
        for (int ni = 0; ni < 4; ++ni)
            bfrag[ni] = __builtin_bit_cast(bf16x8,
                *reinterpret_cast<const u32x4*>(brow[ni] + ks * 32));
        bf16x8 afrag[4];
#pragma unroll
        for (int mi = 0; mi < 4; ++mi) {
            float4 lo = *reinterpret_cast<const float4*>(arow[mi] + ks * 32);
            float4 hi = *reinterpret_cast<const float4*>(arow[mi] + ks * 32 + 4);
            bf16x8 av;
            av[0] = (__bf16)lo.x; av[1] = (__bf16)lo.y;
            av[2] = (__bf16)lo.z; av[3] = (__bf16)lo.w;
            av[4] = (__bf16)hi.x; av[5] = (__bf16)hi.y;
            av[6] = (__bf16)hi.z; av[7] = (__bf16)hi.w;
            afrag[mi] = av;
        }
#pragma unroll
        for (int mi = 0; mi < 4; ++mi)
#pragma unroll
            for (int ni = 0; ni < 4; ++ni)
                acc[mi][ni] = __builtin_amdgcn_mfma_f32_16x16x32_bf16(
                    bfrag[ni], afrag[mi], acc[mi][ni], 0, 0, 0);
    }

    // ---- epilogue stage 1: acc (+bias, ->bf16) into LDS ----
    // lane holds D[m = m_base+mi*16+r][n0..n0+3], n0 = w*64+ni*16+g*4
#pragma unroll
    for (int mi = 0; mi < 4; ++mi)
#pragma unroll
        for (int ni = 0; ni < 4; ++ni) {
            const int n0 = w * 64 + ni * 16 + g * 4;
            const float4 bb = *reinterpret_cast<const float4*>(bv + n0);
            uint2 pk;
            pk.x = (uint32_t)f2bf(acc[mi][ni][0] + bb.x) |
                   ((uint32_t)f2bf(acc[mi][ni][1] + bb.y) << 16);
            pk.y = (uint32_t)f2bf(acc[mi][ni][2] + bb.z) |
                   ((uint32_t)f2bf(acc[mi][ni][3] + bb.w) << 16);
            *reinterpret_cast<uint2*>(&clds[(mi * 16 + r) * 528 + n0 * 2]) = pk;
        }
    __syncthreads();

    // ---- epilogue stage 2: 8 contiguous 4KB chunk stores (one per head) ----
    const int mrow = t >> 2, part = t & 3;
    const int m = m_base + mrow;
    if (m < M_TOTAL) {
        unsigned int um = (unsigned int)m;
        unsigned int c = um / 22050u;
        unsigned int pix = um - c * 22050u;
        const unsigned char* src = &clds[mrow * 528 + part * 16];
#pragma unroll
        for (int hp = 0; hp < 8; ++hp) {
            u32x4 v = *reinterpret_cast<const u32x4*>(src + hp * 64);
            *reinterpret_cast<u32x4*>(
                C + (((size_t)c * 8 + hp) * NV + pix) * 32 + part * 8) = v;
        }
    }
}

// ---------------- offsets + attention weights (q-only, cam-independent) ----------------
__global__ __launch_bounds__(256) void proj_kernel(const float* __restrict__ query,
                                                   const float* __restrict__ qpos,
                                                   const float* __restrict__ Ws,
                                                   const float* __restrict__ b_off,
                                                   const float* __restrict__ Wa,
                                                   const float* __restrict__ ba,
                                                   float* __restrict__ off_ws,
                                                   float* __restrict__ aw_ws) {
    __shared__ float qrow[4][256];
    __shared__ float logits[4][192];
    const int t = threadIdx.x;
    const int qb = blockIdx.x * 4;
#pragma unroll
    for (int j = 0; j < 4; ++j)
        qrow[j][t] = query[(size_t)(qb + j) * 256 + t] + qpos[(size_t)(qb + j) * 256 + t];
    __syncthreads();

    const float invn[3][2] = {{1.f / 168.f, 1.f / 100.f},
                              {1.f / 84.f, 1.f / 50.f},
                              {1.f / 42.f, 1.f / 25.f}};
#pragma unroll
    for (int pass = 0; pass < 3; ++pass) {
        int u = t + pass * 256;
        if (u < 384) {
            float a0 = 0.f, a1 = 0.f, a2 = 0.f, a3 = 0.f;
            for (int k = 0; k < 256; ++k) {
                float w = Ws[k * 384 + u];
                a0 += qrow[0][k] * w; a1 += qrow[1][k] * w;
                a2 += qrow[2][k] * w; a3 += qrow[3][k] * w;
            }
            int lp = u >> 1;               // (h*3+l)*8+p
            int l = (lp >> 3) % 3;
            float inv = invn[l][u & 1];
            float b = b_off[u];
            off_ws[(size_t)(qb + 0) * 384 + u] = (a0 + b) * inv;
            off_ws[(size_t)(qb + 1) * 384 + u] = (a1 + b) * inv;
            off_ws[(size_t)(qb + 2) * 384 + u] = (a2 + b) * inv;
            off_ws[(size_t)(qb + 3) * 384 + u] = (a3 + b) * inv;
        } else if (u < 576) {
            int u2 = u - 384;
            float a0 = 0.f, a1 = 0.f, a2 = 0.f, a3 = 0.f;
            for (int k = 0; k < 256; ++k) {
                float w = Wa[k * 192 + u2];
                a0 += qrow[0][k] * w; a1 += qrow[1][k] * w;
                a2 += qrow[2][k] * w; a3 += qrow[3][k] * w;
            }
            float b = ba[u2];
            logits[0][u2] = a0 + b; logits[1][u2] = a1 + b;
            logits[2][u2] = a2 + b; logits[3][u2] = a3 + b;
        }
    }
    __syncthreads();
    if (t < 32) {
        int jq = t >> 3, h = t & 7;
        float mx = -1e30f;
#pragma unroll
        for (int i = 0; i < 24; ++i) mx = fmaxf(mx, logits[jq][h * 24 + i]);
        float e[24];
        float s = 0.f;
#pragma unroll
        for (int i = 0; i < 24; ++i) { e[i] = __expf(logits[jq][h * 24 + i] - mx); s += e[i]; }
        float inv = 1.0f / s;
#pragma unroll
        for (int i = 0; i < 24; ++i)
            aw_ws[((size_t)(qb + jq) * 8 + h) * 24 + i] = e[i] * inv;
    }
}

// ---------------- bilinear sampling: one (cam,head) plane per block ----------------
__global__ __launch_bounds__(256) void sample_kernel(const unsigned short* __restrict__ val,
                                                     const float* __restrict__ rpc,
                                                     const float* __restrict__ off_ws,
                                                     const float* __restrict__ aw_ws,
                                                     unsigned short* __restrict__ out_cam) {
    const int t = threadIdx.x;
    const int qs = t >> 2;          // 64 q-slots per block
    const int sub = t & 3;          // channel quad within head
    const int p = blockIdx.x;       // 3072 blocks = 8 XCD x 6 groups x 64
    const int x = p & 7;
    const int g = x + 8 * (p >> 9);     // group = c*8 + h
    const int wblk = (p >> 3) & 63;
    const int c = g >> 3, h = g & 7;
    const int q = wblk * 64 + qs;
    const int pair = c * NQ + q;

    float refx[4], refy[4];
    const float* rp = rpc + (size_t)pair * 8;
#pragma unroll
    for (int a = 0; a < 4; ++a) { refx[a] = rp[2 * a]; refy[a] = rp[2 * a + 1]; }

    const unsigned short* vbase = val + (size_t)g * NV * 32 + sub * 8;
    const float* offp = off_ws + (size_t)q * 384 + h * 48;   // [l][p][2]
    const float* awp = aw_ws + ((size_t)q * 8 + h) * 24;

    float acc[8];
#pragma unroll
    for (int i = 0; i < 8; ++i) acc[i] = 0.f;

    const int lw[3] = {168, 84, 42};
    const int lhh[3] = {100, 50, 25};
    const int lst[3] = {0, 16800, 21000};

#pragma unroll
    for (int l = 0; l < 3; ++l) {
        const int w = lw[l], hh = lhh[l];
        const float wf = (float)w, hf = (float)hh;
        const unsigned short* vlev = vbase + (size_t)lst[l] * 32;
#pragma unroll
        for (int pt = 0; pt < 8; ++pt) {
            const int a = pt & 3;
            float ox = offp[(l * 8 + pt) * 2 + 0];
            float oy = offp[(l * 8 + pt) * 2 + 1];
            float xx = fmaf(refx[a] + ox, wf, -0.5f);
            float yy = fmaf(refy[a] + oy, hf, -0.5f);
            float xf = floorf(xx), yf = floorf(yy);
            float lx = xx - xf, ly = yy - yf;
            int x0 = (int)xf, y0 = (int)yf;
            float aww = awp[l * 8 + pt];

            float wx0 = (x0 >= 0 && x0 < w) ? (1.f - lx) : 0.f;
            float wx1 = (x0 >= -1 && x0 < w - 1) ? lx : 0.f;
            float wy0 = ((y0 >= 0 && y0 < hh) ? (1.f - ly) : 0.f) * aww;
            float wy1 = ((y0 >= -1 && y0 < hh - 1) ? ly : 0.f) * aww;

            int x0c = imin(imax(x0, 0), w - 1);
            int x1c = imin(imax(x0 + 1, 0), w - 1);
            int y0c = imin(imax(y0, 0), hh - 1);
            int y1c = imin(imax(y0 + 1, 0), hh - 1);

            int r0 = y0c * w, r1 = y1c * w;
            u32x4 u00 = *reinterpret_cast<const u32x4*>(vlev + (size_t)(r0 + x0c) * 32);
            u32x4 u10 = *reinterpret_cast<const u32x4*>(vlev + (size_t)(r0 + x1c) * 32);
            u32x4 u01 = *reinterpret_cast<const u32x4*>(vlev + (size_t)(r1 + x0c) * 32);
            u32x4 u11 = *reinterpret_cast<const u32x4*>(vlev + (size_t)(r1 + x1c) * 32);

            float w00 = wx0 * wy0, w10 = wx1 * wy0, w01 = wx0 * wy1, w11 = wx1 * wy1;
#pragma unroll
            for (int i = 0; i < 4; ++i) {
                acc[2 * i] += w00 * bf_lo(u00[i]) + w10 * bf_lo(u10[i]) +
                              w01 * bf_lo(u01[i]) + w11 * bf_lo(u11[i]);
                acc[2 * i + 1] += w00 * bf_hi(u00[i]) + w10 * bf_hi(u10[i]) +
                                  w01 * bf_hi(u01[i]) + w11 * bf_hi(u11[i]);
            }
        }
    }

    u32x4 o;
#pragma unroll
    for (int i = 0; i < 4; ++i)
        o[i] = (uint32_t)f2bf(acc[2 * i]) | ((uint32_t)f2bf(acc[2 * i + 1]) << 16);
    *reinterpret_cast<u32x4*>(out_cam + (size_t)pair * 256 + h * 32 + sub * 8) = o;
}

// ---------------- mask-combine over cams + output projection + residual ----------------
__global__ __launch_bounds__(256) void combine_kernel(const unsigned short* __restrict__ out_cam,
                                                      const unsigned char* __restrict__ bev_mask,
                                                      const float* __restrict__ Wo,
                                                      const float* __restrict__ bo,
                                                      const float* __restrict__ query,
                                                      float* __restrict__ out) {
    __shared__ float s_lds[8][256];
    __shared__ unsigned int hitm[8];
    __shared__ float invc[8];
    const int t = threadIdx.x;
    const int qb = blockIdx.x * 8;

    if (t < 8) {
        int q = qb + t;
        unsigned int m = 0;
        int cnt = 0;
        for (int c = 0; c < 6; ++c) {
            const unsigned char* bm = bev_mask + ((size_t)c * NQ + q) * 4;
            if (bm[0] | bm[1] | bm[2] | bm[3]) { m |= (1u << c); cnt++; }
        }
        hitm[t] = m;
        invc[t] = 1.0f / (float)imax(cnt, 1);
    }
    __syncthreads();
#pragma unroll
    for (int j = 0; j < 8; ++j) {
        unsigned int m = hitm[j];
        float ic = invc[j];
        float s = 0.f;
#pragma unroll
        for (int c = 0; c < 6; ++c)
            if ((m >> c) & 1u) {
                unsigned short u = out_cam[((size_t)c * NQ + qb + j) * 256 + t];
                union { uint32_t u; float f; } v; v.u = ((uint32_t)u) << 16;
                s += v.f;
            }
        s_lds[j][t] = s * ic;
    }
    __syncthreads();
    float acc[8] = {0.f, 0.f, 0.f, 0.f, 0.f, 0.f, 0.f, 0.f};
    for (int k = 0; k < 256; ++k) {
        float wv = Wo[k * 256 + t];
#pragma unroll
        for (int j = 0; j < 8; ++j) acc[j] += s_lds[j][k] * wv;
    }
    float bb = bo[t];
#pragma unroll
    for (int j = 0; j < 8; ++j)
        out[(size_t)(qb + j) * 256 + t] = acc[j] + bb + query[(size_t)(qb + j) * 256 + t];
}

extern "C" void kernel_launch(void* const* d_in, const int* in_sizes, int n_in,
                              void* d_out, int out_size, void* d_ws, size_t ws_size,
                              hipStream_t stream) {
    const float* query = (const float*)d_in[0];
    const float* value = (const float*)d_in[2];
    const float* qpos = (const float*)d_in[3];
    const float* rpc = (const float*)d_in[4];
    const unsigned char* bev = (const unsigned char*)d_in[5];
    const float* Wv = (const float*)d_in[8];
    const float* bv = (const float*)d_in[9];
    const float* Ws = (const float*)d_in[10];
    const float* b_off = (const float*)d_in[11];
    const float* Wa = (const float*)d_in[12];
    const float* ba = (const float*)d_in[13];
    const float* Wo = (const float*)d_in[14];
    const float* bo = (const float*)d_in[15];
    float* out = (float*)d_out;

    char* ws = (char*)d_ws;
    unsigned short* val_ws = (unsigned short*)ws;                        // 67,737,600 B
    size_t o = 67737600;
    float* off_ws = (float*)(ws + o);            o += 6291456;           // 4096*384*4
    float* aw_ws = (float*)(ws + o);             o += 3145728;           // 4096*192*4
    unsigned short* out_cam = (unsigned short*)(ws + o); o += 12582912;  // 6*4096*256*2
    unsigned short* WvT = (unsigned short*)(ws + o);                     // 131,072 B

    wvt_kernel<<<256, 256, 0, stream>>>(Wv, WvT);
    proj_kernel<<<NQ / 4, 256, 0, stream>>>(query, qpos, Ws, b_off, Wa, ba, off_ws, aw_ws);
    val_gemm<<<(M_TOTAL + 63) / 64, 256, 0, stream>>>(value, WvT, bv, val_ws);
    sample_kernel<<<3072, 256, 0, stream>>>(val_ws, rpc, off_ws, aw_ws, out_cam);
    combine_kernel<<<NQ / 8, 256, 0, stream>>>(out_cam, bev, Wo, bo, query, out);
}

// Round 7
// 212.555 us; speedup vs baseline: 1.2568x; 1.2144x over previous
//
#include <hip/hip_runtime.h>
#include <stdint.h>

#define NQ 4096
#define NCAM 6
#define NV 22050
#define M_TOTAL (NCAM * NV) /* 132300 */

typedef __bf16 bf16x8 __attribute__((ext_vector_type(8)));
typedef float f32x4 __attribute__((ext_vector_type(4)));
typedef unsigned int u32x4 __attribute__((ext_vector_type(4)));

__device__ __forceinline__ unsigned short f2bf(float f) {
    union { float f; uint32_t u; } v; v.f = f;
    uint32_t u = v.u;
    uint32_t r = (u + 0x7FFFu + ((u >> 16) & 1u)) >> 16;
    return (unsigned short)r;
}
__device__ __forceinline__ float bf_lo(uint32_t u) {
    union { uint32_t u; float f; } v; v.u = u << 16; return v.f;
}
__device__ __forceinline__ float bf_hi(uint32_t u) {
    union { uint32_t u; float f; } v; v.u = u & 0xFFFF0000u; return v.f;
}
__device__ __forceinline__ int imin(int a, int b) { return a < b ? a : b; }
__device__ __forceinline__ int imax(int a, int b) { return a > b ? a : b; }

// ---------------- Wv transpose + bf16 convert (tiny) ----------------
__global__ void wvt_kernel(const float* __restrict__ Wv, unsigned short* __restrict__ WvT) {
    int n = blockIdx.x, k = threadIdx.x;
    WvT[n * 256 + k] = f2bf(Wv[k * 256 + n]);
}

// ---------------- value projection GEMM: val = value @ Wv + bv (bf16 MFMA) ----------------
// A staged through LDS ONCE per block (reg-stage f32->bf16, 1 cvt per element per
// block instead of 4x per wave), double-buffered, one barrier per K-step.
// A LDS layout [c-chunk][row][16B]: frag ds_read_b128 at g*1024+(mi*16+r)*16 is
// 2-way (free); staging global loads stay fully coalesced (4 thr = 128B of a row).
// B direct from global (each B line read exactly once per block either way).
// Epilogue via clds -> 8 contiguous 4KB chunk stores (r6).
__global__ __launch_bounds__(256) void val_gemm(const float* __restrict__ A,
                                                const unsigned short* __restrict__ BT,
                                                const float* __restrict__ bv,
                                                unsigned short* __restrict__ C) {
    __shared__ unsigned char alds[2 * 4096];   // [buf][c][row][16B]
    __shared__ unsigned char clds[64 * 528];
    const int t = threadIdx.x;
    const int w = t >> 6, lane = t & 63;
    const int r = lane & 15, g = lane >> 4;
    const int m_base = blockIdx.x * 64;

    // staging role: row = t>>2, chunk c = t&3 (k-local c*8..c*8+8)
    const int srow = t >> 2, sc = t & 3;
    const float* asrc = A + (size_t)imin(m_base + srow, M_TOTAL - 1) * 256 + sc * 8;
    unsigned char* awr = &alds[sc * 1024 + srow * 16];

    f32x4 acc[4][4];   // [mi][ni]
#pragma unroll
    for (int i = 0; i < 4; ++i)
#pragma unroll
        for (int j = 0; j < 4; ++j) acc[i][j] = (f32x4)0.0f;

    const unsigned short* brow[4];
#pragma unroll
    for (int ni = 0; ni < 4; ++ni)
        brow[ni] = BT + (size_t)(w * 64 + ni * 16 + r) * 256 + g * 8;

    // prologue: stage ks=0 into buf0
    {
        float4 lo = *reinterpret_cast<const float4*>(asrc);
        float4 hi = *reinterpret_cast<const float4*>(asrc + 4);
        bf16x8 av;
        av[0] = (__bf16)lo.x; av[1] = (__bf16)lo.y;
        av[2] = (__bf16)lo.z; av[3] = (__bf16)lo.w;
        av[4] = (__bf16)hi.x; av[5] = (__bf16)hi.y;
        av[6] = (__bf16)hi.z; av[7] = (__bf16)hi.w;
        *reinterpret_cast<u32x4*>(awr) = __builtin_bit_cast(u32x4, av);
    }
    __syncthreads();

#pragma unroll
    for (int ks = 0; ks < 8; ++ks) {
        // issue next-K A loads early (latency hides under B loads + MFMA)
        float4 nlo, nhi;
        if (ks < 7) {
            nlo = *reinterpret_cast<const float4*>(asrc + (ks + 1) * 32);
            nhi = *reinterpret_cast<const float4*>(asrc + (ks + 1) * 32 + 4);
        }
        // B fragments direct from global (L1/L2)
        bf16x8 bfrag[4];
#pragma unroll
        for (int ni = 0; ni < 4; ++ni)
            bfrag[ni] = __builtin_bit_cast(bf16x8,
                *reinterpret_cast<const u32x4*>(brow[ni] + ks * 32));
        // A fragments from LDS
        const unsigned char* abase = &alds[(ks & 1) * 4096 + g * 1024];
        bf16x8 afrag[4];
#pragma unroll
        for (int mi = 0; mi < 4; ++mi)
            afrag[mi] = __builtin_bit_cast(bf16x8,
                *reinterpret_cast<const u32x4*>(abase + (mi * 16 + r) * 16));
#pragma unroll
        for (int mi = 0; mi < 4; ++mi)
#pragma unroll
            for (int ni = 0; ni < 4; ++ni)
                acc[mi][ni] = __builtin_amdgcn_mfma_f32_16x16x32_bf16(
                    bfrag[ni], afrag[mi], acc[mi][ni], 0, 0, 0);
        if (ks < 7) {
            bf16x8 av;
            av[0] = (__bf16)nlo.x; av[1] = (__bf16)nlo.y;
            av[2] = (__bf16)nlo.z; av[3] = (__bf16)nlo.w;
            av[4] = (__bf16)nhi.x; av[5] = (__bf16)nhi.y;
            av[6] = (__bf16)nhi.z; av[7] = (__bf16)nhi.w;
            *reinterpret_cast<u32x4*>(awr + ((ks + 1) & 1) * 4096) =
                __builtin_bit_cast(u32x4, av);
            __syncthreads();   // writes to buf[(ks+1)&1] visible before next iter reads
        }
    }

    // ---- epilogue stage 1: acc (+bias, ->bf16) into LDS ----
    // lane holds D[m = m_base+mi*16+r][n0..n0+3], n0 = w*64+ni*16+g*4
#pragma unroll
    for (int mi = 0; mi < 4; ++mi)
#pragma unroll
        for (int ni = 0; ni < 4; ++ni) {
            const int n0 = w * 64 + ni * 16 + g * 4;
            const float4 bb = *reinterpret_cast<const float4*>(bv + n0);
            uint2 pk;
            pk.x = (uint32_t)f2bf(acc[mi][ni][0] + bb.x) |
                   ((uint32_t)f2bf(acc[mi][ni][1] + bb.y) << 16);
            pk.y = (uint32_t)f2bf(acc[mi][ni][2] + bb.z) |
                   ((uint32_t)f2bf(acc[mi][ni][3] + bb.w) << 16);
            *reinterpret_cast<uint2*>(&clds[(mi * 16 + r) * 528 + n0 * 2]) = pk;
        }
    __syncthreads();

    // ---- epilogue stage 2: 8 contiguous 4KB chunk stores (one per head) ----
    const int mrow = t >> 2, part = t & 3;
    const int m = m_base + mrow;
    if (m < M_TOTAL) {
        unsigned int um = (unsigned int)m;
        unsigned int c = um / 22050u;
        unsigned int pix = um - c * 22050u;
        const unsigned char* src = &clds[mrow * 528 + part * 16];
#pragma unroll
        for (int hp = 0; hp < 8; ++hp) {
            u32x4 v = *reinterpret_cast<const u32x4*>(src + hp * 64);
            *reinterpret_cast<u32x4*>(
                C + (((size_t)c * 8 + hp) * NV + pix) * 32 + part * 8) = v;
        }
    }
}

// ---------------- offsets + attention weights (q-only, cam-independent) ----------------
__global__ __launch_bounds__(256) void proj_kernel(const float* __restrict__ query,
                                                   const float* __restrict__ qpos,
                                                   const float* __restrict__ Ws,
                                                   const float* __restrict__ b_off,
                                                   const float* __restrict__ Wa,
                                                   const float* __restrict__ ba,
                                                   float* __restrict__ off_ws,
                                                   float* __restrict__ aw_ws) {
    __shared__ float qrow[4][256];
    __shared__ float logits[4][192];
    const int t = threadIdx.x;
    const int qb = blockIdx.x * 4;
#pragma unroll
    for (int j = 0; j < 4; ++j)
        qrow[j][t] = query[(size_t)(qb + j) * 256 + t] + qpos[(size_t)(qb + j) * 256 + t];
    __syncthreads();

    const float invn[3][2] = {{1.f / 168.f, 1.f / 100.f},
                              {1.f / 84.f, 1.f / 50.f},
                              {1.f / 42.f, 1.f / 25.f}};
#pragma unroll
    for (int pass = 0; pass < 3; ++pass) {
        int u = t + pass * 256;
        if (u < 384) {
            float a0 = 0.f, a1 = 0.f, a2 = 0.f, a3 = 0.f;
            for (int k = 0; k < 256; ++k) {
                float w = Ws[k * 384 + u];
                a0 += qrow[0][k] * w; a1 += qrow[1][k] * w;
                a2 += qrow[2][k] * w; a3 += qrow[3][k] * w;
            }
            int lp = u >> 1;               // (h*3+l)*8+p
            int l = (lp >> 3) % 3;
            float inv = invn[l][u & 1];
            float b = b_off[u];
            off_ws[(size_t)(qb + 0) * 384 + u] = (a0 + b) * inv;
            off_ws[(size_t)(qb + 1) * 384 + u] = (a1 + b) * inv;
            off_ws[(size_t)(qb + 2) * 384 + u] = (a2 + b) * inv;
            off_ws[(size_t)(qb + 3) * 384 + u] = (a3 + b) * inv;
        } else if (u < 576) {
            int u2 = u - 384;
            float a0 = 0.f, a1 = 0.f, a2 = 0.f, a3 = 0.f;
            for (int k = 0; k < 256; ++k) {
                float w = Wa[k * 192 + u2];
                a0 += qrow[0][k] * w; a1 += qrow[1][k] * w;
                a2 += qrow[2][k] * w; a3 += qrow[3][k] * w;
            }
            float b = ba[u2];
            logits[0][u2] = a0 + b; logits[1][u2] = a1 + b;
            logits[2][u2] = a2 + b; logits[3][u2] = a3 + b;
        }
    }
    __syncthreads();
    if (t < 32) {
        int jq = t >> 3, h = t & 7;
        float mx = -1e30f;
#pragma unroll
        for (int i = 0; i < 24; ++i) mx = fmaxf(mx, logits[jq][h * 24 + i]);
        float e[24];
        float s = 0.f;
#pragma unroll
        for (int i = 0; i < 24; ++i) { e[i] = __expf(logits[jq][h * 24 + i] - mx); s += e[i]; }
        float inv = 1.0f / s;
#pragma unroll
        for (int i = 0; i < 24; ++i)
            aw_ws[((size_t)(qb + jq) * 8 + h) * 24 + i] = e[i] * inv;
    }
}

// ---------------- bilinear sampling: one (cam,head) plane per block ----------------
__global__ __launch_bounds__(256) void sample_kernel(const unsigned short* __restrict__ val,
                                                     const float* __restrict__ rpc,
                                                     const float* __restrict__ off_ws,
                                                     const float* __restrict__ aw_ws,
                                                     unsigned short* __restrict__ out_cam) {
    const int t = threadIdx.x;
    const int qs = t >> 2;          // 64 q-slots per block
    const int sub = t & 3;          // channel quad within head
    const int p = blockIdx.x;       // 3072 blocks = 8 XCD x 6 groups x 64
    const int x = p & 7;
    const int g = x + 8 * (p >> 9);     // group = c*8 + h
    const int wblk = (p >> 3) & 63;
    const int c = g >> 3, h = g & 7;
    const int q = wblk * 64 + qs;
    const int pair = c * NQ + q;

    float refx[4], refy[4];
    const float* rp = rpc + (size_t)pair * 8;
#pragma unroll
    for (int a = 0; a < 4; ++a) { refx[a] = rp[2 * a]; refy[a] = rp[2 * a + 1]; }

    const unsigned short* vbase = val + (size_t)g * NV * 32 + sub * 8;
    const float* offp = off_ws + (size_t)q * 384 + h * 48;   // [l][p][2]
    const float* awp = aw_ws + ((size_t)q * 8 + h) * 24;

    float acc[8];
#pragma unroll
    for (int i = 0; i < 8; ++i) acc[i] = 0.f;

    const int lw[3] = {168, 84, 42};
    const int lhh[3] = {100, 50, 25};
    const int lst[3] = {0, 16800, 21000};

#pragma unroll
    for (int l = 0; l < 3; ++l) {
        const int w = lw[l], hh = lhh[l];
        const float wf = (float)w, hf = (float)hh;
        const unsigned short* vlev = vbase + (size_t)lst[l] * 32;
#pragma unroll
        for (int pt = 0; pt < 8; ++pt) {
            const int a = pt & 3;
            float ox = offp[(l * 8 + pt) * 2 + 0];
            float oy = offp[(l * 8 + pt) * 2 + 1];
            float xx = fmaf(refx[a] + ox, wf, -0.5f);
            float yy = fmaf(refy[a] + oy, hf, -0.5f);
            float xf = floorf(xx), yf = floorf(yy);
            float lx = xx - xf, ly = yy - yf;
            int x0 = (int)xf, y0 = (int)yf;
            float aww = awp[l * 8 + pt];

            float wx0 = (x0 >= 0 && x0 < w) ? (1.f - lx) : 0.f;
            float wx1 = (x0 >= -1 && x0 < w - 1) ? lx : 0.f;
            float wy0 = ((y0 >= 0 && y0 < hh) ? (1.f - ly) : 0.f) * aww;
            float wy1 = ((y0 >= -1 && y0 < hh - 1) ? ly : 0.f) * aww;

            int x0c = imin(imax(x0, 0), w - 1);
            int x1c = imin(imax(x0 + 1, 0), w - 1);
            int y0c = imin(imax(y0, 0), hh - 1);
            int y1c = imin(imax(y0 + 1, 0), hh - 1);

            int r0 = y0c * w, r1 = y1c * w;
            u32x4 u00 = *reinterpret_cast<const u32x4*>(vlev + (size_t)(r0 + x0c) * 32);
            u32x4 u10 = *reinterpret_cast<const u32x4*>(vlev + (size_t)(r0 + x1c) * 32);
            u32x4 u01 = *reinterpret_cast<const u32x4*>(vlev + (size_t)(r1 + x0c) * 32);
            u32x4 u11 = *reinterpret_cast<const u32x4*>(vlev + (size_t)(r1 + x1c) * 32);

            float w00 = wx0 * wy0, w10 = wx1 * wy0, w01 = wx0 * wy1, w11 = wx1 * wy1;
#pragma unroll
            for (int i = 0; i < 4; ++i) {
                acc[2 * i] += w00 * bf_lo(u00[i]) + w10 * bf_lo(u10[i]) +
                              w01 * bf_lo(u01[i]) + w11 * bf_lo(u11[i]);
                acc[2 * i + 1] += w00 * bf_hi(u00[i]) + w10 * bf_hi(u10[i]) +
                                  w01 * bf_hi(u01[i]) + w11 * bf_hi(u11[i]);
            }
        }
    }

    u32x4 o;
#pragma unroll
    for (int i = 0; i < 4; ++i)
        o[i] = (uint32_t)f2bf(acc[2 * i]) | ((uint32_t)f2bf(acc[2 * i + 1]) << 16);
    *reinterpret_cast<u32x4*>(out_cam + (size_t)pair * 256 + h * 32 + sub * 8) = o;
}

// ---------------- mask-combine over cams + output projection + residual ----------------
__global__ __launch_bounds__(256) void combine_kernel(const unsigned short* __restrict__ out_cam,
                                                      const unsigned char* __restrict__ bev_mask,
                                                      const float* __restrict__ Wo,
                                                      const float* __restrict__ bo,
                                                      const float* __restrict__ query,
                                                      float* __restrict__ out) {
    __shared__ float s_lds[8][256];
    __shared__ unsigned int hitm[8];
    __shared__ float invc[8];
    const int t = threadIdx.x;
    const int qb = blockIdx.x * 8;

    if (t < 8) {
        int q = qb + t;
        unsigned int m = 0;
        int cnt = 0;
        for (int c = 0; c < 6; ++c) {
            const unsigned char* bm = bev_mask + ((size_t)c * NQ + q) * 4;
            if (bm[0] | bm[1] | bm[2] | bm[3]) { m |= (1u << c); cnt++; }
        }
        hitm[t] = m;
        invc[t] = 1.0f / (float)imax(cnt, 1);
    }
    __syncthreads();
#pragma unroll
    for (int j = 0; j < 8; ++j) {
        unsigned int m = hitm[j];
        float ic = invc[j];
        float s = 0.f;
#pragma unroll
        for (int c = 0; c < 6; ++c)
            if ((m >> c) & 1u) {
                unsigned short u = out_cam[((size_t)c * NQ + qb + j) * 256 + t];
                union { uint32_t u; float f; } v; v.u = ((uint32_t)u) << 16;
                s += v.f;
            }
        s_lds[j][t] = s * ic;
    }
    __syncthreads();
    float acc[8] = {0.f, 0.f, 0.f, 0.f, 0.f, 0.f, 0.f, 0.f};
    for (int k = 0; k < 256; ++k) {
        float wv = Wo[k * 256 + t];
#pragma unroll
        for (int j = 0; j < 8; ++j) acc[j] += s_lds[j][k] * wv;
    }
    float bb = bo[t];
#pragma unroll
    for (int j = 0; j < 8; ++j)
        out[(size_t)(qb + j) * 256 + t] = acc[j] + bb + query[(size_t)(qb + j) * 256 + t];
}

extern "C" void kernel_launch(void* const* d_in, const int* in_sizes, int n_in,
                              void* d_out, int out_size, void* d_ws, size_t ws_size,
                              hipStream_t stream) {
    const float* query = (const float*)d_in[0];
    const float* value = (const float*)d_in[2];
    const float* qpos = (const float*)d_in[3];
    const float* rpc = (const float*)d_in[4];
    const unsigned char* bev = (const unsigned char*)d_in[5];
    const float* Wv = (const float*)d_in[8];
    const float* bv = (const float*)d_in[9];
    const float* Ws = (const float*)d_in[10];
    const float* b_off = (const float*)d_in[11];
    const float* Wa = (const float*)d_in[12];
    const float* ba = (const float*)d_in[13];
    const float* Wo = (const float*)d_in[14];
    const float* bo = (const float*)d_in[15];
    float* out = (float*)d_out;

    char* ws = (char*)d_ws;
    unsigned short* val_ws = (unsigned short*)ws;                        // 67,737,600 B
    size_t o = 67737600;
    float* off_ws = (float*)(ws + o);            o += 6291456;           // 4096*384*4
    float* aw_ws = (float*)(ws + o);             o += 3145728;           // 4096*192*4
    unsigned short* out_cam = (unsigned short*)(ws + o); o += 12582912;  // 6*4096*256*2
    unsigned short* WvT = (unsigned short*)(ws + o);                     // 131,072 B

    wvt_kernel<<<256, 256, 0, stream>>>(Wv, WvT);
    proj_kernel<<<NQ / 4, 256, 0, stream>>>(query, qpos, Ws, b_off, Wa, ba, off_ws, aw_ws);
    val_gemm<<<(M_TOTAL + 63) / 64, 256, 0, stream>>>(value, WvT, bv, val_ws);
    sample_kernel<<<3072, 256, 0, stream>>>(val_ws, rpc, off_ws, aw_ws, out_cam);
    combine_kernel<<<NQ / 8, 256, 0, stream>>>(out_cam, bev, Wo, bo, query, out);
}

// Round 9
// 201.970 us; speedup vs baseline: 1.3227x; 1.0524x over previous
//
#include <hip/hip_runtime.h>
#include <stdint.h>

#define NQ 4096
#define NCAM 6
#define NV 22050
#define M_TOTAL (NCAM * NV) /* 132300 */

typedef __bf16 bf16x8 __attribute__((ext_vector_type(8)));
typedef float f32x4 __attribute__((ext_vector_type(4)));
typedef unsigned int u32x4 __attribute__((ext_vector_type(4)));

__device__ __forceinline__ unsigned short f2bf(float f) {
    union { float f; uint32_t u; } v; v.f = f;
    uint32_t u = v.u;
    uint32_t r = (u + 0x7FFFu + ((u >> 16) & 1u)) >> 16;
    return (unsigned short)r;
}
__device__ __forceinline__ float bf_lo(uint32_t u) {
    union { uint32_t u; float f; } v; v.u = u << 16; return v.f;
}
__device__ __forceinline__ float bf_hi(uint32_t u) {
    union { uint32_t u; float f; } v; v.u = u & 0xFFFF0000u; return v.f;
}
__device__ __forceinline__ int imin(int a, int b) { return a < b ? a : b; }
__device__ __forceinline__ int imax(int a, int b) { return a > b ? a : b; }

// ---------------- Wv transpose + bf16 convert (tiny) ----------------
__global__ void wvt_kernel(const float* __restrict__ Wv, unsigned short* __restrict__ WvT) {
    int n = blockIdx.x, k = threadIdx.x;
    WvT[n * 256 + k] = f2bf(Wv[k * 256 + n]);
}

// ---------------- value projection GEMM: val = value @ Wv + bv (bf16 MFMA) ----------------
// Exact r7 structure (passed, val_gemm ~60us): A staged through LDS once per block,
// double-buffered; B direct from global; bf16 output planes val2[c][h][pix][32ch];
// epilogue via clds -> 8 contiguous 4KB chunk stores.
__global__ __launch_bounds__(256) void val_gemm(const float* __restrict__ A,
                                                const unsigned short* __restrict__ BT,
                                                const float* __restrict__ bv,
                                                unsigned short* __restrict__ C) {
    __shared__ unsigned char alds[2 * 4096];   // [buf][c][row][16B]
    __shared__ unsigned char clds[64 * 528];
    const int t = threadIdx.x;
    const int w = t >> 6, lane = t & 63;
    const int r = lane & 15, g = lane >> 4;
    const int m_base = blockIdx.x * 64;

    const int srow = t >> 2, sc = t & 3;
    const float* asrc = A + (size_t)imin(m_base + srow, M_TOTAL - 1) * 256 + sc * 8;
    unsigned char* awr = &alds[sc * 1024 + srow * 16];

    f32x4 acc[4][4];
#pragma unroll
    for (int i = 0; i < 4; ++i)
#pragma unroll
        for (int j = 0; j < 4; ++j) acc[i][j] = (f32x4)0.0f;

    const unsigned short* brow[4];
#pragma unroll
    for (int ni = 0; ni < 4; ++ni)
        brow[ni] = BT + (size_t)(w * 64 + ni * 16 + r) * 256 + g * 8;

    {
        float4 lo = *reinterpret_cast<const float4*>(asrc);
        float4 hi = *reinterpret_cast<const float4*>(asrc + 4);
        bf16x8 av;
        av[0] = (__bf16)lo.x; av[1] = (__bf16)lo.y;
        av[2] = (__bf16)lo.z; av[3] = (__bf16)lo.w;
        av[4] = (__bf16)hi.x; av[5] = (__bf16)hi.y;
        av[6] = (__bf16)hi.z; av[7] = (__bf16)hi.w;
        *reinterpret_cast<u32x4*>(awr) = __builtin_bit_cast(u32x4, av);
    }
    __syncthreads();

#pragma unroll
    for (int ks = 0; ks < 8; ++ks) {
        float4 nlo, nhi;
        if (ks < 7) {
            nlo = *reinterpret_cast<const float4*>(asrc + (ks + 1) * 32);
            nhi = *reinterpret_cast<const float4*>(asrc + (ks + 1) * 32 + 4);
        }
        bf16x8 bfrag[4];
#pragma unroll
        for (int ni = 0; ni < 4; ++ni)
            bfrag[ni] = __builtin_bit_cast(bf16x8,
                *reinterpret_cast<const u32x4*>(brow[ni] + ks * 32));
        const unsigned char* abase = &alds[(ks & 1) * 4096 + g * 1024];
        bf16x8 afrag[4];
#pragma unroll
        for (int mi = 0; mi < 4; ++mi)
            afrag[mi] = __builtin_bit_cast(bf16x8,
                *reinterpret_cast<const u32x4*>(abase + (mi * 16 + r) * 16));
#pragma unroll
        for (int mi = 0; mi < 4; ++mi)
#pragma unroll
            for (int ni = 0; ni < 4; ++ni)
                acc[mi][ni] = __builtin_amdgcn_mfma_f32_16x16x32_bf16(
                    bfrag[ni], afrag[mi], acc[mi][ni], 0, 0, 0);
        if (ks < 7) {
            bf16x8 av;
            av[0] = (__bf16)nlo.x; av[1] = (__bf16)nlo.y;
            av[2] = (__bf16)nlo.z; av[3] = (__bf16)nlo.w;
            av[4] = (__bf16)nhi.x; av[5] = (__bf16)nhi.y;
            av[6] = (__bf16)nhi.z; av[7] = (__bf16)nhi.w;
            *reinterpret_cast<u32x4*>(awr + ((ks + 1) & 1) * 4096) =
                __builtin_bit_cast(u32x4, av);
            __syncthreads();
        }
    }

    // epilogue stage 1: acc (+bias, ->bf16) into LDS
#pragma unroll
    for (int mi = 0; mi < 4; ++mi)
#pragma unroll
        for (int ni = 0; ni < 4; ++ni) {
            const int n0 = w * 64 + ni * 16 + g * 4;
            const float4 bb = *reinterpret_cast<const float4*>(bv + n0);
            uint2 pk;
            pk.x = (uint32_t)f2bf(acc[mi][ni][0] + bb.x) |
                   ((uint32_t)f2bf(acc[mi][ni][1] + bb.y) << 16);
            pk.y = (uint32_t)f2bf(acc[mi][ni][2] + bb.z) |
                   ((uint32_t)f2bf(acc[mi][ni][3] + bb.w) << 16);
            *reinterpret_cast<uint2*>(&clds[(mi * 16 + r) * 528 + n0 * 2]) = pk;
        }
    __syncthreads();

    // epilogue stage 2: 8 contiguous 4KB chunk stores (one per head)
    const int mrow = t >> 2, part = t & 3;
    const int m = m_base + mrow;
    if (m < M_TOTAL) {
        unsigned int um = (unsigned int)m;
        unsigned int c = um / 22050u;
        unsigned int pix = um - c * 22050u;
        const unsigned char* src = &clds[mrow * 528 + part * 16];
#pragma unroll
        for (int hp = 0; hp < 8; ++hp) {
            u32x4 v = *reinterpret_cast<const u32x4*>(src + hp * 64);
            *reinterpret_cast<u32x4*>(
                C + (((size_t)c * 8 + hp) * NV + pix) * 32 + part * 8) = v;
        }
    }
}

// ---------------- offsets + attention weights (q-only, cam-independent) ----------------
__global__ __launch_bounds__(256) void proj_kernel(const float* __restrict__ query,
                                                   const float* __restrict__ qpos,
                                                   const float* __restrict__ Ws,
                                                   const float* __restrict__ b_off,
                                                   const float* __restrict__ Wa,
                                                   const float* __restrict__ ba,
                                                   float* __restrict__ off_ws,
                                                   float* __restrict__ aw_ws) {
    __shared__ float qrow[4][256];
    __shared__ float logits[4][192];
    const int t = threadIdx.x;
    const int qb = blockIdx.x * 4;
#pragma unroll
    for (int j = 0; j < 4; ++j)
        qrow[j][t] = query[(size_t)(qb + j) * 256 + t] + qpos[(size_t)(qb + j) * 256 + t];
    __syncthreads();

    const float invn[3][2] = {{1.f / 168.f, 1.f / 100.f},
                              {1.f / 84.f, 1.f / 50.f},
                              {1.f / 42.f, 1.f / 25.f}};
#pragma unroll
    for (int pass = 0; pass < 3; ++pass) {
        int u = t + pass * 256;
        if (u < 384) {
            float a0 = 0.f, a1 = 0.f, a2 = 0.f, a3 = 0.f;
            for (int k = 0; k < 256; ++k) {
                float w = Ws[k * 384 + u];
                a0 += qrow[0][k] * w; a1 += qrow[1][k] * w;
                a2 += qrow[2][k] * w; a3 += qrow[3][k] * w;
            }
            int lp = u >> 1;
            int l = (lp >> 3) % 3;
            float inv = invn[l][u & 1];
            float b = b_off[u];
            off_ws[(size_t)(qb + 0) * 384 + u] = (a0 + b) * inv;
            off_ws[(size_t)(qb + 1) * 384 + u] = (a1 + b) * inv;
            off_ws[(size_t)(qb + 2) * 384 + u] = (a2 + b) * inv;
            off_ws[(size_t)(qb + 3) * 384 + u] = (a3 + b) * inv;
        } else if (u < 576) {
            int u2 = u - 384;
            float a0 = 0.f, a1 = 0.f, a2 = 0.f, a3 = 0.f;
            for (int k = 0; k < 256; ++k) {
                float w = Wa[k * 192 + u2];
                a0 += qrow[0][k] * w; a1 += qrow[1][k] * w;
                a2 += qrow[2][k] * w; a3 += qrow[3][k] * w;
            }
            float b = ba[u2];
            logits[0][u2] = a0 + b; logits[1][u2] = a1 + b;
            logits[2][u2] = a2 + b; logits[3][u2] = a3 + b;
        }
    }
    __syncthreads();
    if (t < 32) {
        int jq = t >> 3, h = t & 7;
        float mx = -1e30f;
#pragma unroll
        for (int i = 0; i < 24; ++i) mx = fmaxf(mx, logits[jq][h * 24 + i]);
        float e[24];
        float s = 0.f;
#pragma unroll
        for (int i = 0; i < 24; ++i) { e[i] = __expf(logits[jq][h * 24 + i] - mx); s += e[i]; }
        float inv = 1.0f / s;
#pragma unroll
        for (int i = 0; i < 24; ++i)
            aw_ws[((size_t)(qb + jq) * 8 + h) * 24 + i] = e[i] * inv;
    }
}

// ---------------- bilinear sampling: f32/u32 descriptor phase + r7 gather math ----------------
// Phase 1: each lane builds 6 of its query's 24 descriptors: {o00,o10,o01,o11} u32
// pixel indices (level start folded) + {w00,w10,w01,w11} f32 weights (validity and
// aww folded). LDS stride 49/query -> 2-way bank alias (free). Phase 2: per point
// 2x ds_read_b128 + 4x dwordx4 bf16 corner loads + f32 FMA (r7-verbatim math).
__global__ __launch_bounds__(256) void sample_kernel(const unsigned short* __restrict__ val,
                                                     const float* __restrict__ rpc,
                                                     const float* __restrict__ off_ws,
                                                     const float* __restrict__ aw_ws,
                                                     unsigned short* __restrict__ out_cam) {
    __shared__ u32x4 dlds[64 * 49];   // [qs][pt*2 + j], qs stride 49
    const int t = threadIdx.x;
    const int qs = t >> 2;          // 64 q-slots per block
    const int sub = t & 3;          // channel quad within head
    const int p = blockIdx.x;       // 3072 = 8 XCD x 6 groups x 64
    const int x = p & 7;
    const int g = x + 8 * (p >> 9);     // group = c*8 + h
    const int wblk = (p >> 3) & 63;
    const int c = g >> 3, h = g & 7;
    const int q = wblk * 64 + qs;
    const int pair = c * NQ + q;

    // ---- phase 1: descriptors for pts sub*6 .. sub*6+5 of query qs ----
    {
        const float* rp = rpc + (size_t)pair * 8;
        float4 r01 = *reinterpret_cast<const float4*>(rp);      // a0.x a0.y a1.x a1.y
        float4 r23 = *reinterpret_cast<const float4*>(rp + 4);  // a2.x a2.y a3.x a3.y
        const float* offp = off_ws + (size_t)q * 384 + h * 48;
        const float* awp = aw_ws + ((size_t)q * 8 + h) * 24;
#pragma unroll
        for (int i = 0; i < 6; ++i) {
            const int pt = sub * 6 + i;
            const int lvl = pt >> 3;
            const int w = 168 >> lvl, hh = 100 >> lvl;
            const int lst = (lvl == 0) ? 0 : ((lvl == 1) ? 16800 : 21000);
            const int a = pt & 3;
            float rx01 = (a & 1) ? r01.z : r01.x;
            float ry01 = (a & 1) ? r01.w : r01.y;
            float rx23 = (a & 1) ? r23.z : r23.x;
            float ry23 = (a & 1) ? r23.w : r23.y;
            float rx = (a & 2) ? rx23 : rx01;
            float ry = (a & 2) ? ry23 : ry01;

            float ox = offp[pt * 2 + 0];
            float oy = offp[pt * 2 + 1];
            float aww = awp[pt];
            float xx = fmaf(rx + ox, (float)w, -0.5f);
            float yy = fmaf(ry + oy, (float)hh, -0.5f);
            float xf = floorf(xx), yf = floorf(yy);
            float lx = xx - xf, ly = yy - yf;
            int x0 = (int)xf, y0 = (int)yf;

            float wx0 = (x0 >= 0 && x0 < w) ? (1.f - lx) : 0.f;
            float wx1 = (x0 >= -1 && x0 < w - 1) ? lx : 0.f;
            float wy0 = ((y0 >= 0 && y0 < hh) ? (1.f - ly) : 0.f) * aww;
            float wy1 = ((y0 >= -1 && y0 < hh - 1) ? ly : 0.f) * aww;

            int x0c = imin(imax(x0, 0), w - 1);
            int x1c = imin(imax(x0 + 1, 0), w - 1);
            int y0c = imin(imax(y0, 0), hh - 1);
            int y1c = imin(imax(y0 + 1, 0), hh - 1);
            int r0 = lst + y0c * w, r1 = lst + y1c * w;

            u32x4 doff;
            doff[0] = (unsigned)(r0 + x0c);
            doff[1] = (unsigned)(r0 + x1c);
            doff[2] = (unsigned)(r1 + x0c);
            doff[3] = (unsigned)(r1 + x1c);
            f32x4 dw;
            dw[0] = wx0 * wy0; dw[1] = wx1 * wy0;
            dw[2] = wx0 * wy1; dw[3] = wx1 * wy1;
            dlds[qs * 49 + pt * 2 + 0] = doff;
            dlds[qs * 49 + pt * 2 + 1] = __builtin_bit_cast(u32x4, dw);
        }
    }
    __syncthreads();

    // ---- phase 2: gather (r7 math) ----
    const unsigned short* vg = val + (size_t)g * NV * 32 + sub * 8;
    float acc[8];
#pragma unroll
    for (int i = 0; i < 8; ++i) acc[i] = 0.f;

#pragma unroll
    for (int pt = 0; pt < 24; ++pt) {
        u32x4 doff = dlds[qs * 49 + pt * 2 + 0];
        f32x4 dw = __builtin_bit_cast(f32x4, dlds[qs * 49 + pt * 2 + 1]);
        u32x4 u00 = *reinterpret_cast<const u32x4*>(vg + (size_t)doff[0] * 32);
        u32x4 u10 = *reinterpret_cast<const u32x4*>(vg + (size_t)doff[1] * 32);
        u32x4 u01 = *reinterpret_cast<const u32x4*>(vg + (size_t)doff[2] * 32);
        u32x4 u11 = *reinterpret_cast<const u32x4*>(vg + (size_t)doff[3] * 32);
        float w00 = dw[0], w10 = dw[1], w01 = dw[2], w11 = dw[3];
#pragma unroll
        for (int i = 0; i < 4; ++i) {
            acc[2 * i] += w00 * bf_lo(u00[i]) + w10 * bf_lo(u10[i]) +
                          w01 * bf_lo(u01[i]) + w11 * bf_lo(u11[i]);
            acc[2 * i + 1] += w00 * bf_hi(u00[i]) + w10 * bf_hi(u10[i]) +
                              w01 * bf_hi(u01[i]) + w11 * bf_hi(u11[i]);
        }
    }

    u32x4 o;
#pragma unroll
    for (int i = 0; i < 4; ++i)
        o[i] = (uint32_t)f2bf(acc[2 * i]) | ((uint32_t)f2bf(acc[2 * i + 1]) << 16);
    *reinterpret_cast<u32x4*>(out_cam + (size_t)pair * 256 + h * 32 + sub * 8) = o;
}

// ---------------- mask-combine over cams + output projection + residual ----------------
__global__ __launch_bounds__(256) void combine_kernel(const unsigned short* __restrict__ out_cam,
                                                      const unsigned char* __restrict__ bev_mask,
                                                      const float* __restrict__ Wo,
                                                      const float* __restrict__ bo,
                                                      const float* __restrict__ query,
                                                      float* __restrict__ out) {
    __shared__ float s_lds[8][256];
    __shared__ unsigned int hitm[8];
    __shared__ float invc[8];
    const int t = threadIdx.x;
    const int qb = blockIdx.x * 8;

    if (t < 8) {
        int q = qb + t;
        unsigned int m = 0;
        int cnt = 0;
        for (int c = 0; c < 6; ++c) {
            const unsigned char* bm = bev_mask + ((size_t)c * NQ + q) * 4;
            if (bm[0] | bm[1] | bm[2] | bm[3]) { m |= (1u << c); cnt++; }
        }
        hitm[t] = m;
        invc[t] = 1.0f / (float)imax(cnt, 1);
    }
    __syncthreads();
#pragma unroll
    for (int j = 0; j < 8; ++j) {
        unsigned int m = hitm[j];
        float ic = invc[j];
        float s = 0.f;
#pragma unroll
        for (int c = 0; c < 6; ++c)
            if ((m >> c) & 1u) {
                unsigned short u = out_cam[((size_t)c * NQ + qb + j) * 256 + t];
                union { uint32_t u; float f; } v; v.u = ((uint32_t)u) << 16;
                s += v.f;
            }
        s_lds[j][t] = s * ic;
    }
    __syncthreads();
    float acc[8] = {0.f, 0.f, 0.f, 0.f, 0.f, 0.f, 0.f, 0.f};
    for (int k = 0; k < 256; ++k) {
        float wv = Wo[k * 256 + t];
#pragma unroll
        for (int j = 0; j < 8; ++j) acc[j] += s_lds[j][k] * wv;
    }
    float bb = bo[t];
#pragma unroll
    for (int j = 0; j < 8; ++j)
        out[(size_t)(qb + j) * 256 + t] = acc[j] + bb + query[(size_t)(qb + j) * 256 + t];
}

extern "C" void kernel_launch(void* const* d_in, const int* in_sizes, int n_in,
                              void* d_out, int out_size, void* d_ws, size_t ws_size,
                              hipStream_t stream) {
    const float* query = (const float*)d_in[0];
    const float* value = (const float*)d_in[2];
    const float* qpos = (const float*)d_in[3];
    const float* rpc = (const float*)d_in[4];
    const unsigned char* bev = (const unsigned char*)d_in[5];
    const float* Wv = (const float*)d_in[8];
    const float* bv = (const float*)d_in[9];
    const float* Ws = (const float*)d_in[10];
    const float* b_off = (const float*)d_in[11];
    const float* Wa = (const float*)d_in[12];
    const float* ba = (const float*)d_in[13];
    const float* Wo = (const float*)d_in[14];
    const float* bo = (const float*)d_in[15];
    float* out = (float*)d_out;

    char* ws = (char*)d_ws;
    unsigned short* val_ws = (unsigned short*)ws;                        // 67,737,600 B (bf16 planes)
    size_t o = 67737600;
    float* off_ws = (float*)(ws + o);            o += 6291456;           // 4096*384*4
    float* aw_ws = (float*)(ws + o);             o += 3145728;           // 4096*192*4
    unsigned short* out_cam = (unsigned short*)(ws + o); o += 12582912;  // 6*4096*256*2
    unsigned short* WvT = (unsigned short*)(ws + o);                     // 131,072 B

    wvt_kernel<<<256, 256, 0, stream>>>(Wv, WvT);
    proj_kernel<<<NQ / 4, 256, 0, stream>>>(query, qpos, Ws, b_off, Wa, ba, off_ws, aw_ws);
    val_gemm<<<(M_TOTAL + 63) / 64, 256, 0, stream>>>(value, WvT, bv, val_ws);
    sample_kernel<<<3072, 256, 0, stream>>>(val_ws, rpc, off_ws, aw_ws, out_cam);
    combine_kernel<<<NQ / 8, 256, 0, stream>>>(out_cam, bev, Wo, bo, query, out);
}